// Round 15
// baseline (162.566 us; speedup 1.0000x reference)
//
#include <hip/hip_runtime.h>
#include <hip/hip_fp16.h>

#define B_     4096
#define INE_   4096
#define INBR_  8192
#define D_     2048
#define KE_    50
#define KPAD_  52
#define CAP_   512
#define NSL_   4

// ---------- helpers ----------
__device__ __forceinline__ float2 unpackh2(unsigned u) {
  __half2 h = __builtin_bit_cast(__half2, u);
  return __half22float2(h);
}

// direct global->LDS DMA, 16 B per lane (dest = wave-uniform base + lane*16)
__device__ __forceinline__ void gload_lds16(const float* g, float* l) {
  __builtin_amdgcn_global_load_lds(
      (const __attribute__((address_space(1))) void*)g,
      (__attribute__((address_space(3))) void*)l, 16, 0, 0);
}

// ---------- top-k body ----------
// Excitation (kpad>1): packed muT[13][2048] = uint4 {u16 off[4], f16 val[4]},
//   off = BYTE offset of column in an f32 row: 4*c (max 16380, fits u16).
// Inhibition (kpad==1): out_off[row] = RAW COLUMN index, out_val = -50*w.
__device__ void topk_body(const float* __restrict__ W, int row, int k, int kpad,
                          float hi, float t0, float vscale,
                          uint4* __restrict__ muT,
                          unsigned* __restrict__ out_off, float* __restrict__ out_val)
{
  const int t = threadIdx.x;
  const float* wr = W + (size_t)row * INE_;

  __shared__ float cval[CAP_];
  __shared__ int   ccol[CAP_];
  __shared__ int   scnt;
  __shared__ int   red[4];

  float thr = t0;
  int M = 0;
  for (int attempt = 0; attempt < 8; ++attempt) {
    int local = 0;
    #pragma unroll
    for (int j = 0; j < 4; ++j) {
      float4 w4 = *reinterpret_cast<const float4*>(wr + 4 * (t + 256 * j));
      local += (w4.x > thr) + (w4.y > thr) + (w4.z > thr) + (w4.w > thr);
    }
    #pragma unroll
    for (int off = 32; off > 0; off >>= 1) local += __shfl_down(local, off);
    if ((t & 63) == 0) red[t >> 6] = local;
    __syncthreads();
    M = red[0] + red[1] + red[2] + red[3];
    __syncthreads();
    if (M >= k && M <= CAP_) break;
    if (M < k) thr = hi - (hi - thr) * 4.0f;
    else       thr = hi - (hi - thr) * 0.5f;
  }

  if (t == 0) scnt = 0;
  __syncthreads();
  #pragma unroll
  for (int j = 0; j < 4; ++j) {
    int cbase = 4 * (t + 256 * j);
    float4 w4 = *reinterpret_cast<const float4*>(wr + cbase);
    float wv[4] = {w4.x, w4.y, w4.z, w4.w};
    #pragma unroll
    for (int q = 0; q < 4; ++q) {
      if (wv[q] > thr) {
        int pp = atomicAdd(&scnt, 1);
        if (pp < CAP_) { cval[pp] = wv[q]; ccol[pp] = cbase + q; }
      }
    }
  }
  __syncthreads();
  M = scnt < CAP_ ? scnt : CAP_;

  for (int i = t; i < M; i += 256) {
    float wi = cval[i]; int ci = ccol[i];
    int rank = 0;
    for (int m = 0; m < M; ++m) {
      float wm = cval[m]; int cm = ccol[m];
      rank += (wm > wi || (wm == wi && cm < ci)) ? 1 : 0;
    }
    if (rank < k) {
      unsigned c = (unsigned)ci;
      if (kpad == 1) {
        out_off[row] = c;
        out_val[row] = wi * vscale;
      } else {
        char* rec = (char*)muT + ((size_t)(rank >> 2) * D_ + row) * 16;
        reinterpret_cast<unsigned short*>(rec)[rank & 3] =
            (unsigned short)(c << 2);
        reinterpret_cast<__half*>(rec)[4 + (rank & 3)] =
            __float2half_rn(wi * vscale);
      }
    }
  }
  if (kpad > 1 && t < kpad - k) {
    int slot = k + t;
    char* rec = (char*)muT + ((size_t)(slot >> 2) * D_ + row) * 16;
    reinterpret_cast<unsigned short*>(rec)[slot & 3] = 0;
    reinterpret_cast<__half*>(rec)[4 + (slot & 3)] = __float2half_rn(0.0f);
  }
}

// ---------- K1: combined prep ----------
__global__ __launch_bounds__(256) void prep_kernel(
    const float* __restrict__ wexc, const float* __restrict__ winh,
    const float* __restrict__ wblk,
    uint4* __restrict__ muT,
    unsigned* __restrict__ so_inh, float* __restrict__ vi_inh,
    float* __restrict__ wdiag)
{
  const int bid = blockIdx.x;
  const float hi = 0.015625f;
  if (bid < 2048) {
    topk_body(wexc, bid, KE_, KPAD_, hi, hi * (1.0f - 200.0f / 4096.0f), 1.0f,
              muT, nullptr, nullptr);
  } else if (bid < 4096) {
    topk_body(winh, bid - 2048, 1, 1, hi, hi * (1.0f - 48.0f / 4096.0f), -50.0f,
              nullptr, so_inh, vi_inh);
  } else {
    const int t = threadIdx.x;
    #pragma unroll
    for (int j = 0; j < 8; ++j) {
      int d = t + 256 * j;
      float4 w = *reinterpret_cast<const float4*>(wblk + (size_t)d * (INBR_ + 4));
      reinterpret_cast<float4*>(wdiag)[d] = w;
    }
  }
}

// ---------- fused E+I+BR+stats (4 rows/block, 64 KiB f32 LDS, DMA-staged) ----------
// LDS: xs_f[4][4096] row-major f32. Column c of row r at byte 16384*r + 4*c.
#define LDSF(OFF) (*reinterpret_cast<const float*>(ldsb + (OFF)))

__global__ __launch_bounds__(512, 4) void fused_ei(
    const float* __restrict__ xe, const float* __restrict__ xi,
    const float* __restrict__ xbr, const float* __restrict__ wdiag,
    const uint4* __restrict__ muT,
    const unsigned* __restrict__ so_inh, const float* __restrict__ vi_inh,
    __half* __restrict__ act_h, float* __restrict__ sums_p,
    float* __restrict__ sumsq_p)
{
  __shared__ float xs_f[16384];           // 64 KiB -> 2 blocks/CU
  const int t  = threadIdx.x;
  const int b0 = blockIdx.x * 4;

  float acc[4][4];
  #pragma unroll
  for (int r = 0; r < 4; ++r)
    #pragma unroll
    for (int b = 0; b < 4; ++b) acc[r][b] = 0.0f;

  const char* ldsb = reinterpret_cast<const char*>(xs_f);

  // ---- stage xe via direct global->LDS DMA (no VALU, no VGPR round-trip) ----
  {
    const int wave = t >> 6, lane = t & 63;
    #pragma unroll
    for (int j = 0; j < 8; ++j) {
      int k   = wave * 8 + j;             // 0..63 chunks of 256 floats
      int row = k >> 4;                   // 0..3
      int cin = (k & 15) << 8;            // 0,256,...,3840
      const float* g = xe + (size_t)(b0 + row) * INE_ + cin + lane * 4;
      float*       l = xs_f + row * 4096 + cin + lane * 4;
      gload_lds16(g, l);
    }
  }
  __syncthreads();                         // drains the DMA (vmcnt) + barrier

  // ---- phase E: 13 iterations, packed metadata, f32 gathers ----
  for (int ii = 0; ii < KPAD_ / 4; ++ii) {
    uint4 m[4];
    #pragma unroll
    for (int r = 0; r < 4; ++r) m[r] = muT[ii * D_ + t + 512 * r];
    #pragma unroll
    for (int r = 0; r < 4; ++r) {
      unsigned o0 = m[r].x & 0xFFFFu, o1 = m[r].x >> 16;
      unsigned o2 = m[r].y & 0xFFFFu, o3 = m[r].y >> 16;
      float2 vA = unpackh2(m[r].z);
      float2 vB = unpackh2(m[r].w);
      // 16 independent ds_read_b32 (base + imm offsets 0/16K/32K/48K)
      float g00 = LDSF(o0), g01 = LDSF(o0 + 16384),
            g02 = LDSF(o0 + 32768), g03 = LDSF(o0 + 49152);
      float g10 = LDSF(o1), g11 = LDSF(o1 + 16384),
            g12 = LDSF(o1 + 32768), g13 = LDSF(o1 + 49152);
      float g20 = LDSF(o2), g21 = LDSF(o2 + 16384),
            g22 = LDSF(o2 + 32768), g23 = LDSF(o2 + 49152);
      float g30 = LDSF(o3), g31 = LDSF(o3 + 16384),
            g32 = LDSF(o3 + 32768), g33 = LDSF(o3 + 49152);
      acc[r][0] = fmaf(g00, vA.x, acc[r][0]);
      acc[r][1] = fmaf(g01, vA.x, acc[r][1]);
      acc[r][2] = fmaf(g02, vA.x, acc[r][2]);
      acc[r][3] = fmaf(g03, vA.x, acc[r][3]);
      acc[r][0] = fmaf(g10, vA.y, acc[r][0]);
      acc[r][1] = fmaf(g11, vA.y, acc[r][1]);
      acc[r][2] = fmaf(g12, vA.y, acc[r][2]);
      acc[r][3] = fmaf(g13, vA.y, acc[r][3]);
      acc[r][0] = fmaf(g20, vB.x, acc[r][0]);
      acc[r][1] = fmaf(g21, vB.x, acc[r][1]);
      acc[r][2] = fmaf(g22, vB.x, acc[r][2]);
      acc[r][3] = fmaf(g23, vB.x, acc[r][3]);
      acc[r][0] = fmaf(g30, vB.y, acc[r][0]);
      acc[r][1] = fmaf(g31, vB.y, acc[r][1]);
      acc[r][2] = fmaf(g32, vB.y, acc[r][2]);
      acc[r][3] = fmaf(g33, vB.y, acc[r][3]);
    }
  }

  // NOTE: acc[r][j] currently means (d = t+512r, batch row b0+j) where the
  // gathered value g_rj came from LDS row j. LDS row j holds xe[b0+j]. Correct.

  // ---- phase I: direct scattered xi gathers (register-only, post-E) ----
  {
    unsigned ci[4]; float viv[4];
    #pragma unroll
    for (int r = 0; r < 4; ++r) {
      ci[r]  = so_inh[t + 512 * r];
      viv[r] = vi_inh[t + 512 * r];
    }
    float xg0[4], xg1[4], xg2[4], xg3[4];
    #pragma unroll
    for (int b = 0; b < 4; ++b) {
      const float* xrow = xi + (size_t)(b0 + b) * INE_;
      xg0[b] = xrow[ci[0]];
      xg1[b] = xrow[ci[1]];
      xg2[b] = xrow[ci[2]];
      xg3[b] = xrow[ci[3]];
    }
    #pragma unroll
    for (int b = 0; b < 4; ++b) {
      acc[0][b] = fmaf(xg0[b], viv[0], acc[0][b]);
      acc[1][b] = fmaf(xg1[b], viv[1], acc[1][b]);
      acc[2][b] = fmaf(xg2[b], viv[2], acc[2][b]);
      acc[3][b] = fmaf(xg3[b], viv[3], acc[3][b]);
    }
  }

  // ---- phase BR: block-diagonal depolarization (coalesced stream) ----
  #pragma unroll
  for (int r = 0; r < 4; ++r) {
    const int d = t + 512 * r;
    float4 wb4 = reinterpret_cast<const float4*>(wdiag)[d];
    #pragma unroll
    for (int b = 0; b < 4; ++b) {
      float4 xb4 = *reinterpret_cast<const float4*>(
          xbr + (size_t)(b0 + b) * INBR_ + 4 * d);
      acc[r][b] += xb4.x * wb4.x + xb4.y * wb4.y + xb4.z * wb4.z + xb4.w * wb4.w;
    }
  }

  // ---- write act (f16) + sliced BN partials ----
  const int slice = blockIdx.x & (NSL_ - 1);
  #pragma unroll
  for (int r = 0; r < 4; ++r) {
    const int d = t + 512 * r;
    float s = 0.0f, s2 = 0.0f;
    #pragma unroll
    for (int b = 0; b < 4; ++b) {
      float a = acc[r][b];
      act_h[(size_t)(b0 + b) * D_ + d] = __float2half_rn(a);
      s += a;
      s2 = fmaf(a, a, s2);
    }
    atomicAdd(&sums_p[slice * D_ + d], s);
    atomicAdd(&sumsq_p[slice * D_ + d], s2);
  }
}

// ---------- tail: finalize stats + normalize + sigmoid -> d_out ----------
__global__ __launch_bounds__(256) void tail_kernel(
    const __half* __restrict__ act_h, float* __restrict__ out,
    const float* __restrict__ sums_p, const float* __restrict__ sumsq_p,
    const float* __restrict__ gamma, const float* __restrict__ beta)
{
  __shared__ float scsh[2 * D_];
  const int tid = threadIdx.x;
  #pragma unroll
  for (int j = 0; j < 8; ++j) {
    int d = tid + 256 * j;
    float s = 0.0f, s2 = 0.0f;
    #pragma unroll
    for (int sl = 0; sl < NSL_; ++sl) {
      s  += sums_p[sl * D_ + d];
      s2 += sumsq_p[sl * D_ + d];
    }
    float mean = s  * (1.0f / B_);
    float var  = s2 * (1.0f / B_) - mean * mean;
    float rstd = rsqrtf(var + 1e-5f);
    float sc   = gamma[d] * rstd;
    scsh[2 * d]     = sc;
    scsh[2 * d + 1] = fmaf(-mean, sc, beta[d]);
  }
  __syncthreads();

  const int r0 = blockIdx.x * 8;
  for (int rr = 0; rr < 8; ++rr) {
    const uint2* ap = reinterpret_cast<const uint2*>(act_h + (size_t)(r0 + rr) * D_);
    float4*      op = reinterpret_cast<float4*>(out + (size_t)(r0 + rr) * D_);
    #pragma unroll
    for (int i2 = 0; i2 < 2; ++i2) {
      int i = tid + 256 * i2;
      uint2 aw = ap[i];
      float2 f0 = unpackh2(aw.x);
      float2 f1 = unpackh2(aw.y);
      const float4* sp = reinterpret_cast<const float4*>(scsh + 8 * i);
      float4 s0 = sp[0];
      float4 s1 = sp[1];
      float z0 = fmaf(f0.x, s0.x, s0.y);
      float z1 = fmaf(f0.y, s0.z, s0.w);
      float z2 = fmaf(f1.x, s1.x, s1.y);
      float z3 = fmaf(f1.y, s1.z, s1.w);
      float4 o;
      o.x = 1.0f / (1.0f + __expf(-z0));
      o.y = 1.0f / (1.0f + __expf(-z1));
      o.z = 1.0f / (1.0f + __expf(-z2));
      o.w = 1.0f / (1.0f + __expf(-z3));
      op[i] = o;
    }
  }
}

extern "C" void kernel_launch(void* const* d_in, const int* in_sizes, int n_in,
                              void* d_out, int out_size, void* d_ws, size_t ws_size,
                              hipStream_t stream) {
  const float* xe    = (const float*)d_in[0];
  const float* xi    = (const float*)d_in[1];
  const float* xbr   = (const float*)d_in[2];
  const float* wexc  = (const float*)d_in[3];
  const float* winh  = (const float*)d_in[4];
  const float* wblk  = (const float*)d_in[5];
  const float* gamma = (const float*)d_in[6];
  const float* beta  = (const float*)d_in[7];
  float* out = (float*)d_out;

  char* ws = (char*)d_ws;
  uint4*    muT     = (uint4*)   (ws + 0);         // [13][2048] uint4
  unsigned* so_inh  = (unsigned*)(ws + 425984);
  float*    vi_inh  = (float*)   (ws + 434176);
  float*    wdiag   = (float*)   (ws + 442368);    // ends 475136
  float*    sums_p  = (float*)   (ws + 475136);    // [4][2048] f32
  float*    sumsq_p = (float*)   (ws + 507904);    // [4][2048] f32 (ends 540672)
  __half*   act_h   = (__half*)  (ws + 1048576);   // [4096][2048] f16 = 16 MiB

  hipMemsetAsync(sums_p, 0, 2 * NSL_ * D_ * sizeof(float), stream);

  prep_kernel<<<dim3(4097), dim3(256), 0, stream>>>(
      wexc, winh, wblk, muT, so_inh, vi_inh, wdiag);
  fused_ei<<<dim3(B_ / 4), dim3(512), 0, stream>>>(
      xe, xi, xbr, wdiag, muT, so_inh, vi_inh, act_h, sums_p, sumsq_p);
  tail_kernel<<<dim3(512), dim3(256), 0, stream>>>(
      act_h, out, sums_p, sumsq_p, gamma, beta);
}

// Round 16
// 125.827 us; speedup vs baseline: 1.2920x; 1.2920x over previous
//
#include <hip/hip_runtime.h>
#include <hip/hip_fp16.h>

#define B_     4096
#define INE_   4096
#define INBR_  8192
#define D_     2048
#define KE_    50
#define KPAD_  52
#define CAP_   512
#define NSL_   4

// ---------- helpers ----------
__device__ __forceinline__ unsigned packh2(float a, float b) {
  __half2 h = __floats2half2_rn(a, b);
  return __builtin_bit_cast(unsigned, h);
}
__device__ __forceinline__ float2 unpackh2(unsigned u) {
  __half2 h = __builtin_bit_cast(__half2, u);
  return __half22float2(h);
}

// ---------- top-k body ----------
// Excitation (kpad>1): packed muT[13][2048] = uint4 {u16 off[4], f16 val[4]},
//   off = 4-row LDS byte offset: ((c>>2)<<3) | ((c&3)<<13)  (max 32760).
// Inhibition (kpad==1): out_off[row] = RAW COLUMN index, out_val = -50*w.
__device__ void topk_body(const float* __restrict__ W, int row, int k, int kpad,
                          float hi, float t0, float vscale,
                          uint4* __restrict__ muT,
                          unsigned* __restrict__ out_off, float* __restrict__ out_val)
{
  const int t = threadIdx.x;
  const float* wr = W + (size_t)row * INE_;

  __shared__ float cval[CAP_];
  __shared__ int   ccol[CAP_];
  __shared__ int   scnt;
  __shared__ int   red[4];

  float thr = t0;
  int M = 0;
  for (int attempt = 0; attempt < 8; ++attempt) {
    int local = 0;
    #pragma unroll
    for (int j = 0; j < 4; ++j) {
      float4 w4 = *reinterpret_cast<const float4*>(wr + 4 * (t + 256 * j));
      local += (w4.x > thr) + (w4.y > thr) + (w4.z > thr) + (w4.w > thr);
    }
    #pragma unroll
    for (int off = 32; off > 0; off >>= 1) local += __shfl_down(local, off);
    if ((t & 63) == 0) red[t >> 6] = local;
    __syncthreads();
    M = red[0] + red[1] + red[2] + red[3];
    __syncthreads();
    if (M >= k && M <= CAP_) break;
    if (M < k) thr = hi - (hi - thr) * 4.0f;
    else       thr = hi - (hi - thr) * 0.5f;
  }

  if (t == 0) scnt = 0;
  __syncthreads();
  #pragma unroll
  for (int j = 0; j < 4; ++j) {
    int cbase = 4 * (t + 256 * j);
    float4 w4 = *reinterpret_cast<const float4*>(wr + cbase);
    float wv[4] = {w4.x, w4.y, w4.z, w4.w};
    #pragma unroll
    for (int q = 0; q < 4; ++q) {
      if (wv[q] > thr) {
        int pp = atomicAdd(&scnt, 1);
        if (pp < CAP_) { cval[pp] = wv[q]; ccol[pp] = cbase + q; }
      }
    }
  }
  __syncthreads();
  M = scnt < CAP_ ? scnt : CAP_;

  for (int i = t; i < M; i += 256) {
    float wi = cval[i]; int ci = ccol[i];
    int rank = 0;
    for (int m = 0; m < M; ++m) {
      float wm = cval[m]; int cm = ccol[m];
      rank += (wm > wi || (wm == wi && cm < ci)) ? 1 : 0;
    }
    if (rank < k) {
      unsigned c = (unsigned)ci;
      if (kpad == 1) {
        out_off[row] = c;
        out_val[row] = wi * vscale;
      } else {
        unsigned off = ((c >> 2) << 3) | ((c & 3u) << 13);
        char* rec = (char*)muT + ((size_t)(rank >> 2) * D_ + row) * 16;
        reinterpret_cast<unsigned short*>(rec)[rank & 3] = (unsigned short)off;
        reinterpret_cast<__half*>(rec)[4 + (rank & 3)] =
            __float2half_rn(wi * vscale);
      }
    }
  }
  if (kpad > 1 && t < kpad - k) {
    int slot = k + t;
    char* rec = (char*)muT + ((size_t)(slot >> 2) * D_ + row) * 16;
    reinterpret_cast<unsigned short*>(rec)[slot & 3] = 0;
    reinterpret_cast<__half*>(rec)[4 + (slot & 3)] = __float2half_rn(0.0f);
  }
}

// ---------- K1: combined prep ----------
__global__ __launch_bounds__(256) void prep_kernel(
    const float* __restrict__ wexc, const float* __restrict__ winh,
    const float* __restrict__ wblk,
    uint4* __restrict__ muT,
    unsigned* __restrict__ so_inh, float* __restrict__ vi_inh,
    float* __restrict__ wdiag)
{
  const int bid = blockIdx.x;
  const float hi = 0.015625f;
  if (bid < 2048) {
    topk_body(wexc, bid, KE_, KPAD_, hi, hi * (1.0f - 200.0f / 4096.0f), 1.0f,
              muT, nullptr, nullptr);
  } else if (bid < 4096) {
    topk_body(winh, bid - 2048, 1, 1, hi, hi * (1.0f - 48.0f / 4096.0f), -50.0f,
              nullptr, so_inh, vi_inh);
  } else {
    const int t = threadIdx.x;
    #pragma unroll
    for (int j = 0; j < 8; ++j) {
      int d = t + 256 * j;
      float4 w = *reinterpret_cast<const float4*>(wblk + (size_t)d * (INBR_ + 4));
      reinterpret_cast<float4*>(wdiag)[d] = w;
    }
  }
}

// ---------- fused E+I+BR+stats (4 rows/block, 32 KiB LDS, 1 barrier) ----------
// LDS: column c at words {2*s(c), 2*s(c)+1}, s(c)=(c>>2)|((c&3)<<10);
// word 2*s(c)+p = half2(row 2p, 2p+1).
__device__ __forceinline__ uint2 ld8(const char* ldsb, unsigned off) {
  return *reinterpret_cast<const uint2*>(ldsb + off);
}

#define FMA4(R, G, WV) do {                                                \
    float2 f0 = unpackh2((G).x), f1 = unpackh2((G).y);                     \
    acc[R][0] = fmaf(f0.x, (WV), acc[R][0]);                               \
    acc[R][1] = fmaf(f0.y, (WV), acc[R][1]);                               \
    acc[R][2] = fmaf(f1.x, (WV), acc[R][2]);                               \
    acc[R][3] = fmaf(f1.y, (WV), acc[R][3]);                               \
  } while (0)

// one E iteration (ii may be runtime; acc indices compile-time)
#define E_ITER(II) do {                                                    \
    uint4 m_[4];                                                           \
    _Pragma("unroll")                                                      \
    for (int r = 0; r < 4; ++r) m_[r] = muT[(II) * D_ + t + 512 * r];      \
    _Pragma("unroll")                                                      \
    for (int half = 0; half < 2; ++half) {                                 \
      uint2 g_[2][4];                                                      \
      _Pragma("unroll")                                                    \
      for (int rr = 0; rr < 2; ++rr) {                                     \
        const int r = 2 * half + rr;                                       \
        g_[rr][0] = ld8(ldsb, m_[r].x & 0xFFFFu);                          \
        g_[rr][1] = ld8(ldsb, m_[r].x >> 16);                              \
        g_[rr][2] = ld8(ldsb, m_[r].y & 0xFFFFu);                          \
        g_[rr][3] = ld8(ldsb, m_[r].y >> 16);                              \
      }                                                                    \
      _Pragma("unroll")                                                    \
      for (int rr = 0; rr < 2; ++rr) {                                     \
        const int r = 2 * half + rr;                                       \
        float2 vA = unpackh2(m_[r].z);                                     \
        float2 vB = unpackh2(m_[r].w);                                     \
        FMA4(r, g_[rr][0], vA.x);                                          \
        FMA4(r, g_[rr][1], vA.y);                                          \
        FMA4(r, g_[rr][2], vB.x);                                          \
        FMA4(r, g_[rr][3], vB.y);                                          \
      }                                                                    \
    }                                                                      \
  } while (0)

__global__ __launch_bounds__(512, 4) void fused_ei(
    const float* __restrict__ xe, const float* __restrict__ xi,
    const float* __restrict__ xbr, const float* __restrict__ wdiag,
    const uint4* __restrict__ muT,
    const unsigned* __restrict__ so_inh, const float* __restrict__ vi_inh,
    __half* __restrict__ act_h, float* __restrict__ sums_p,
    float* __restrict__ sumsq_p)
{
  __shared__ unsigned xs[8192];           // 32 KiB
  const int t  = threadIdx.x;
  const int b0 = blockIdx.x * 4;
  const int p  = t & 1;
  const int Q  = t >> 1;

  float acc[4][4];
  #pragma unroll
  for (int r = 0; r < 4; ++r)
    #pragma unroll
    for (int b = 0; b < 4; ++b) acc[r][b] = 0.0f;

  const char* ldsb = reinterpret_cast<const char*>(xs);

  // ---- stage xe into LDS ----
  {
    const float* r0p = xe + (size_t)(b0 + 2 * p)     * INE_;
    const float* r1p = xe + (size_t)(b0 + 2 * p + 1) * INE_;
    #pragma unroll
    for (int m = 0; m < 4; ++m) {
      int c0 = 4 * Q + 1024 * m;
      float4 fa = *reinterpret_cast<const float4*>(r0p + c0);
      float4 fb = *reinterpret_cast<const float4*>(r1p + c0);
      int wb = 2 * (Q + 256 * m) + p;
      xs[wb]        = packh2(fa.x, fb.x);
      xs[wb + 2048] = packh2(fa.y, fb.y);
      xs[wb + 4096] = packh2(fa.z, fb.z);
      xs[wb + 6144] = packh2(fa.w, fb.w);
    }
  }

  // inhibition metadata (pre-barrier: tiny, L2-hot; drain is negligible)
  unsigned ci[4]; float viv[4];
  #pragma unroll
  for (int r = 0; r < 4; ++r) {
    ci[r]  = so_inh[t + 512 * r];
    viv[r] = vi_inh[t + 512 * r];
  }
  __syncthreads();   // drains everything above (vmcnt(0) before s_barrier)

  // ---- POST-barrier prefetch issue: these loads stay in flight under E ----
  float4 wd[4];
  #pragma unroll
  for (int r = 0; r < 4; ++r)
    wd[r] = reinterpret_cast<const float4*>(wdiag)[t + 512 * r];
  float4 xbA[4][2];                       // xbr rows b0+0, b0+1
  #pragma unroll
  for (int r = 0; r < 4; ++r)
    #pragma unroll
    for (int b = 0; b < 2; ++b)
      xbA[r][b] = *reinterpret_cast<const float4*>(
          xbr + (size_t)(b0 + b) * INBR_ + 4 * (t + 512 * r));
  float xg[4][4];                         // xi scattered gathers
  #pragma unroll
  for (int b = 0; b < 4; ++b) {
    const float* xrow = xi + (size_t)(b0 + b) * INE_;
    xg[0][b] = xrow[ci[0]];
    xg[1][b] = xrow[ci[1]];
    xg[2][b] = xrow[ci[2]];
    xg[3][b] = xrow[ci[3]];
  }

  // ---- phase E part 1: ii = 0..5 (hides prefetch latency + BW) ----
  for (int ii = 0; ii < 6; ++ii) E_ITER(ii);

  // ---- consume xbr half A; issue half B ----
  #pragma unroll
  for (int r = 0; r < 4; ++r)
    #pragma unroll
    for (int b = 0; b < 2; ++b) {
      float4 x = xbA[r][b];
      acc[r][b] += x.x * wd[r].x + x.y * wd[r].y + x.z * wd[r].z + x.w * wd[r].w;
    }
  float4 xbB[4][2];                       // xbr rows b0+2, b0+3
  #pragma unroll
  for (int r = 0; r < 4; ++r)
    #pragma unroll
    for (int b = 0; b < 2; ++b)
      xbB[r][b] = *reinterpret_cast<const float4*>(
          xbr + (size_t)(b0 + 2 + b) * INBR_ + 4 * (t + 512 * r));

  // ---- phase E part 2: ii = 6..12 (hides half-B latency + BW) ----
  for (int ii = 6; ii < KPAD_ / 4; ++ii) E_ITER(ii);

  // ---- consume xi ----
  #pragma unroll
  for (int r = 0; r < 4; ++r)
    #pragma unroll
    for (int b = 0; b < 4; ++b)
      acc[r][b] = fmaf(xg[r][b], viv[r], acc[r][b]);

  // ---- consume xbr half B ----
  #pragma unroll
  for (int r = 0; r < 4; ++r)
    #pragma unroll
    for (int b = 0; b < 2; ++b) {
      float4 x = xbB[r][b];
      acc[r][2 + b] += x.x * wd[r].x + x.y * wd[r].y + x.z * wd[r].z + x.w * wd[r].w;
    }

  // ---- write act (f16) + sliced BN partials ----
  const int slice = blockIdx.x & (NSL_ - 1);
  #pragma unroll
  for (int r = 0; r < 4; ++r) {
    const int d = t + 512 * r;
    float s = 0.0f, s2 = 0.0f;
    #pragma unroll
    for (int b = 0; b < 4; ++b) {
      float a = acc[r][b];
      act_h[(size_t)(b0 + b) * D_ + d] = __float2half_rn(a);
      s += a;
      s2 = fmaf(a, a, s2);
    }
    atomicAdd(&sums_p[slice * D_ + d], s);
    atomicAdd(&sumsq_p[slice * D_ + d], s2);
  }
}

// ---------- tail: finalize stats + normalize + sigmoid -> d_out ----------
__global__ __launch_bounds__(256) void tail_kernel(
    const __half* __restrict__ act_h, float* __restrict__ out,
    const float* __restrict__ sums_p, const float* __restrict__ sumsq_p,
    const float* __restrict__ gamma, const float* __restrict__ beta)
{
  __shared__ float scsh[2 * D_];
  const int tid = threadIdx.x;
  #pragma unroll
  for (int j = 0; j < 8; ++j) {
    int d = tid + 256 * j;
    float s = 0.0f, s2 = 0.0f;
    #pragma unroll
    for (int sl = 0; sl < NSL_; ++sl) {
      s  += sums_p[sl * D_ + d];
      s2 += sumsq_p[sl * D_ + d];
    }
    float mean = s  * (1.0f / B_);
    float var  = s2 * (1.0f / B_) - mean * mean;
    float rstd = rsqrtf(var + 1e-5f);
    float sc   = gamma[d] * rstd;
    scsh[2 * d]     = sc;
    scsh[2 * d + 1] = fmaf(-mean, sc, beta[d]);
  }
  __syncthreads();

  const int r0 = blockIdx.x * 8;
  for (int rr = 0; rr < 8; ++rr) {
    const uint2* ap = reinterpret_cast<const uint2*>(act_h + (size_t)(r0 + rr) * D_);
    float4*      op = reinterpret_cast<float4*>(out + (size_t)(r0 + rr) * D_);
    #pragma unroll
    for (int i2 = 0; i2 < 2; ++i2) {
      int i = tid + 256 * i2;
      uint2 aw = ap[i];
      float2 f0 = unpackh2(aw.x);
      float2 f1 = unpackh2(aw.y);
      const float4* sp = reinterpret_cast<const float4*>(scsh + 8 * i);
      float4 s0 = sp[0];
      float4 s1 = sp[1];
      float z0 = fmaf(f0.x, s0.x, s0.y);
      float z1 = fmaf(f0.y, s0.z, s0.w);
      float z2 = fmaf(f1.x, s1.x, s1.y);
      float z3 = fmaf(f1.y, s1.z, s1.w);
      float4 o;
      o.x = 1.0f / (1.0f + __expf(-z0));
      o.y = 1.0f / (1.0f + __expf(-z1));
      o.z = 1.0f / (1.0f + __expf(-z2));
      o.w = 1.0f / (1.0f + __expf(-z3));
      op[i] = o;
    }
  }
}

extern "C" void kernel_launch(void* const* d_in, const int* in_sizes, int n_in,
                              void* d_out, int out_size, void* d_ws, size_t ws_size,
                              hipStream_t stream) {
  const float* xe    = (const float*)d_in[0];
  const float* xi    = (const float*)d_in[1];
  const float* xbr   = (const float*)d_in[2];
  const float* wexc  = (const float*)d_in[3];
  const float* winh  = (const float*)d_in[4];
  const float* wblk  = (const float*)d_in[5];
  const float* gamma = (const float*)d_in[6];
  const float* beta  = (const float*)d_in[7];
  float* out = (float*)d_out;

  char* ws = (char*)d_ws;
  uint4*    muT     = (uint4*)   (ws + 0);         // [13][2048] uint4
  unsigned* so_inh  = (unsigned*)(ws + 425984);
  float*    vi_inh  = (float*)   (ws + 434176);
  float*    wdiag   = (float*)   (ws + 442368);    // ends 475136
  float*    sums_p  = (float*)   (ws + 475136);    // [4][2048] f32
  float*    sumsq_p = (float*)   (ws + 507904);    // [4][2048] f32 (ends 540672)
  __half*   act_h   = (__half*)  (ws + 1048576);   // [4096][2048] f16 = 16 MiB

  hipMemsetAsync(sums_p, 0, 2 * NSL_ * D_ * sizeof(float), stream);

  prep_kernel<<<dim3(4097), dim3(256), 0, stream>>>(
      wexc, winh, wblk, muT, so_inh, vi_inh, wdiag);
  fused_ei<<<dim3(B_ / 4), dim3(512), 0, stream>>>(
      xe, xi, xbr, wdiag, muT, so_inh, vi_inh, act_h, sums_p, sumsq_p);
  tail_kernel<<<dim3(512), dim3(256), 0, stream>>>(
      act_h, out, sums_p, sumsq_p, gamma, beta);
}

// Round 18
// 124.583 us; speedup vs baseline: 1.3049x; 1.0100x over previous
//
#include <hip/hip_runtime.h>
#include <hip/hip_fp16.h>

#define B_     4096
#define INE_   4096
#define INBR_  8192
#define D_     2048
#define KE_    50
#define KPAD_  52
#define CAP_   512
#define NSL_   4

// ---------- helpers ----------
__device__ __forceinline__ unsigned packh2(float a, float b) {
  __half2 h = __floats2half2_rn(a, b);
  return __builtin_bit_cast(unsigned, h);
}
__device__ __forceinline__ float2 unpackh2(unsigned u) {
  __half2 h = __builtin_bit_cast(__half2, u);
  return __half22float2(h);
}

// ---------- top-k body ----------
// Excitation (kpad>1): packed muT[13][2048] = uint4 {u16 off[4], f16 val[4]},
//   off = 4-row LDS byte offset: ((c>>2)<<3) | ((c&3)<<13)  (max 32760).
// Inhibition (kpad==1): out_off[row] = RAW COLUMN index, out_val = -50*w.
__device__ void topk_body(const float* __restrict__ W, int row, int k, int kpad,
                          float hi, float t0, float vscale,
                          uint4* __restrict__ muT,
                          unsigned* __restrict__ out_off, float* __restrict__ out_val)
{
  const int t = threadIdx.x;
  const float* wr = W + (size_t)row * INE_;

  __shared__ float cval[CAP_];
  __shared__ int   ccol[CAP_];
  __shared__ int   scnt;
  __shared__ int   red[4];

  float thr = t0;
  int M = 0;
  for (int attempt = 0; attempt < 8; ++attempt) {
    int local = 0;
    #pragma unroll
    for (int j = 0; j < 4; ++j) {
      float4 w4 = *reinterpret_cast<const float4*>(wr + 4 * (t + 256 * j));
      local += (w4.x > thr) + (w4.y > thr) + (w4.z > thr) + (w4.w > thr);
    }
    #pragma unroll
    for (int off = 32; off > 0; off >>= 1) local += __shfl_down(local, off);
    if ((t & 63) == 0) red[t >> 6] = local;
    __syncthreads();
    M = red[0] + red[1] + red[2] + red[3];
    __syncthreads();
    if (M >= k && M <= CAP_) break;
    if (M < k) thr = hi - (hi - thr) * 4.0f;
    else       thr = hi - (hi - thr) * 0.5f;
  }

  if (t == 0) scnt = 0;
  __syncthreads();
  #pragma unroll
  for (int j = 0; j < 4; ++j) {
    int cbase = 4 * (t + 256 * j);
    float4 w4 = *reinterpret_cast<const float4*>(wr + cbase);
    float wv[4] = {w4.x, w4.y, w4.z, w4.w};
    #pragma unroll
    for (int q = 0; q < 4; ++q) {
      if (wv[q] > thr) {
        int pp = atomicAdd(&scnt, 1);
        if (pp < CAP_) { cval[pp] = wv[q]; ccol[pp] = cbase + q; }
      }
    }
  }
  __syncthreads();
  M = scnt < CAP_ ? scnt : CAP_;

  for (int i = t; i < M; i += 256) {
    float wi = cval[i]; int ci = ccol[i];
    int rank = 0;
    for (int m = 0; m < M; ++m) {
      float wm = cval[m]; int cm = ccol[m];
      rank += (wm > wi || (wm == wi && cm < ci)) ? 1 : 0;
    }
    if (rank < k) {
      unsigned c = (unsigned)ci;
      if (kpad == 1) {
        out_off[row] = c;
        out_val[row] = wi * vscale;
      } else {
        unsigned off = ((c >> 2) << 3) | ((c & 3u) << 13);
        char* rec = (char*)muT + ((size_t)(rank >> 2) * D_ + row) * 16;
        reinterpret_cast<unsigned short*>(rec)[rank & 3] = (unsigned short)off;
        reinterpret_cast<__half*>(rec)[4 + (rank & 3)] =
            __float2half_rn(wi * vscale);
      }
    }
  }
  if (kpad > 1 && t < kpad - k) {
    int slot = k + t;
    char* rec = (char*)muT + ((size_t)(slot >> 2) * D_ + row) * 16;
    reinterpret_cast<unsigned short*>(rec)[slot & 3] = 0;
    reinterpret_cast<__half*>(rec)[4 + (slot & 3)] = __float2half_rn(0.0f);
  }
}

// ---------- K1: combined prep ----------
__global__ __launch_bounds__(256) void prep_kernel(
    const float* __restrict__ wexc, const float* __restrict__ winh,
    const float* __restrict__ wblk,
    uint4* __restrict__ muT,
    unsigned* __restrict__ so_inh, float* __restrict__ vi_inh,
    float* __restrict__ wdiag)
{
  const int bid = blockIdx.x;
  const float hi = 0.015625f;
  if (bid < 2048) {
    topk_body(wexc, bid, KE_, KPAD_, hi, hi * (1.0f - 200.0f / 4096.0f), 1.0f,
              muT, nullptr, nullptr);
  } else if (bid < 4096) {
    topk_body(winh, bid - 2048, 1, 1, hi, hi * (1.0f - 48.0f / 4096.0f), -50.0f,
              nullptr, so_inh, vi_inh);
  } else {
    const int t = threadIdx.x;
    #pragma unroll
    for (int j = 0; j < 8; ++j) {
      int d = t + 256 * j;
      float4 w = *reinterpret_cast<const float4*>(wblk + (size_t)d * (INBR_ + 4));
      reinterpret_cast<float4*>(wdiag)[d] = w;
    }
  }
}

// ---------- fused E+I+BR+stats (4 rows/block, 32 KiB LDS, 1 barrier) ----------
// LDS: column c at words {2*s(c), 2*s(c)+1}, s(c)=(c>>2)|((c&3)<<10);
// word 2*s(c)+p = half2(row 2p, 2p+1).
__device__ __forceinline__ uint2 ld8(const char* ldsb, unsigned off) {
  return *reinterpret_cast<const uint2*>(ldsb + off);
}

#define FMA4(R, G, WV) do {                                                \
    float2 f0 = unpackh2((G).x), f1 = unpackh2((G).y);                     \
    acc[R][0] = fmaf(f0.x, (WV), acc[R][0]);                               \
    acc[R][1] = fmaf(f0.y, (WV), acc[R][1]);                               \
    acc[R][2] = fmaf(f1.x, (WV), acc[R][2]);                               \
    acc[R][3] = fmaf(f1.y, (WV), acc[R][3]);                               \
  } while (0)

__global__ __launch_bounds__(512, 4) void fused_ei(
    const float* __restrict__ xe, const float* __restrict__ xi,
    const float* __restrict__ xbr, const float* __restrict__ wdiag,
    const uint4* __restrict__ muT,
    const unsigned* __restrict__ so_inh, const float* __restrict__ vi_inh,
    __half* __restrict__ act_h, float* __restrict__ sums_p,
    float* __restrict__ sumsq_p)
{
  __shared__ unsigned xs[8192];           // 32 KiB
  const int t  = threadIdx.x;
  const int b0 = blockIdx.x * 4;
  const int p  = t & 1;
  const int Q  = t >> 1;

  float acc[4][4];
  #pragma unroll
  for (int r = 0; r < 4; ++r)
    #pragma unroll
    for (int b = 0; b < 4; ++b) acc[r][b] = 0.0f;

  const char* ldsb = reinterpret_cast<const char*>(xs);

  // ---- stage xe into LDS (the only staged input) ----
  {
    const float* r0p = xe + (size_t)(b0 + 2 * p)     * INE_;
    const float* r1p = xe + (size_t)(b0 + 2 * p + 1) * INE_;
    #pragma unroll
    for (int m = 0; m < 4; ++m) {
      int c0 = 4 * Q + 1024 * m;
      float4 fa = *reinterpret_cast<const float4*>(r0p + c0);
      float4 fb = *reinterpret_cast<const float4*>(r1p + c0);
      int wb = 2 * (Q + 256 * m) + p;
      xs[wb]        = packh2(fa.x, fb.x);
      xs[wb + 2048] = packh2(fa.y, fb.y);
      xs[wb + 4096] = packh2(fa.z, fb.z);
      xs[wb + 6144] = packh2(fa.w, fb.w);
    }
  }

  // ---- phase I setup: direct scattered xi gathers, issued EARLY so the
  //      ~300cy HBM/L2 latency hides under phase E (T14 pattern) ----
  unsigned ci[4]; float viv[4];
  #pragma unroll
  for (int r = 0; r < 4; ++r) {
    ci[r]  = so_inh[t + 512 * r];
    viv[r] = vi_inh[t + 512 * r];
  }
  float xg0[4], xg1[4], xg2[4], xg3[4];
  #pragma unroll
  for (int b = 0; b < 4; ++b) {
    const float* xrow = xi + (size_t)(b0 + b) * INE_;
    xg0[b] = xrow[ci[0]];
    xg1[b] = xrow[ci[1]];
    xg2[b] = xrow[ci[2]];
    xg3[b] = xrow[ci[3]];
  }
  __syncthreads();                         // xe staged; ONLY barrier

  // ---- phase E: 13 iterations, packed metadata ----
  for (int ii = 0; ii < KPAD_ / 4; ++ii) {
    uint4 m[4];
    #pragma unroll
    for (int r = 0; r < 4; ++r) m[r] = muT[ii * D_ + t + 512 * r];
    #pragma unroll
    for (int half = 0; half < 2; ++half) {
      uint2 g[2][4];
      #pragma unroll
      for (int rr = 0; rr < 2; ++rr) {
        const int r = 2 * half + rr;
        g[rr][0] = ld8(ldsb, m[r].x & 0xFFFFu);
        g[rr][1] = ld8(ldsb, m[r].x >> 16);
        g[rr][2] = ld8(ldsb, m[r].y & 0xFFFFu);
        g[rr][3] = ld8(ldsb, m[r].y >> 16);
      }
      #pragma unroll
      for (int rr = 0; rr < 2; ++rr) {
        const int r = 2 * half + rr;
        float2 vA = unpackh2(m[r].z);
        float2 vB = unpackh2(m[r].w);
        FMA4(r, g[rr][0], vA.x);
        FMA4(r, g[rr][1], vA.y);
        FMA4(r, g[rr][2], vB.x);
        FMA4(r, g[rr][3], vB.y);
      }
    }
  }

  // ---- phase I: consume prefetched gathers (register-only) ----
  #pragma unroll
  for (int b = 0; b < 4; ++b) {
    acc[0][b] = fmaf(xg0[b], viv[0], acc[0][b]);
    acc[1][b] = fmaf(xg1[b], viv[1], acc[1][b]);
    acc[2][b] = fmaf(xg2[b], viv[2], acc[2][b]);
    acc[3][b] = fmaf(xg3[b], viv[3], acc[3][b]);
  }

  // ---- phase BR: block-diagonal depolarization (coalesced stream) ----
  #pragma unroll
  for (int r = 0; r < 4; ++r) {
    const int d = t + 512 * r;
    float4 wb4 = reinterpret_cast<const float4*>(wdiag)[d];
    #pragma unroll
    for (int b = 0; b < 4; ++b) {
      float4 xb4 = *reinterpret_cast<const float4*>(
          xbr + (size_t)(b0 + b) * INBR_ + 4 * d);
      acc[r][b] += xb4.x * wb4.x + xb4.y * wb4.y + xb4.z * wb4.z + xb4.w * wb4.w;
    }
  }

  // ---- write act (f16) + sliced BN partials (stats from f32 acc) ----
  const int slice = blockIdx.x & (NSL_ - 1);
  #pragma unroll
  for (int r = 0; r < 4; ++r) {
    const int d = t + 512 * r;
    float s = 0.0f, s2 = 0.0f;
    #pragma unroll
    for (int b = 0; b < 4; ++b) {
      float a = acc[r][b];
      act_h[(size_t)(b0 + b) * D_ + d] = __float2half_rn(a);
      s += a;
      s2 = fmaf(a, a, s2);
    }
    atomicAdd(&sums_p[slice * D_ + d], s);
    atomicAdd(&sumsq_p[slice * D_ + d], s2);
  }
}

// ---------- tail: finalize stats + normalize + sigmoid -> d_out ----------
__global__ __launch_bounds__(256) void tail_kernel(
    const __half* __restrict__ act_h, float* __restrict__ out,
    const float* __restrict__ sums_p, const float* __restrict__ sumsq_p,
    const float* __restrict__ gamma, const float* __restrict__ beta)
{
  __shared__ float scsh[2 * D_];
  const int tid = threadIdx.x;
  #pragma unroll
  for (int j = 0; j < 8; ++j) {
    int d = tid + 256 * j;
    float s = 0.0f, s2 = 0.0f;
    #pragma unroll
    for (int sl = 0; sl < NSL_; ++sl) {
      s  += sums_p[sl * D_ + d];
      s2 += sumsq_p[sl * D_ + d];
    }
    float mean = s  * (1.0f / B_);
    float var  = s2 * (1.0f / B_) - mean * mean;
    float rstd = rsqrtf(var + 1e-5f);
    float sc   = gamma[d] * rstd;
    scsh[2 * d]     = sc;
    scsh[2 * d + 1] = fmaf(-mean, sc, beta[d]);
  }
  __syncthreads();

  const int r0 = blockIdx.x * 8;
  for (int rr = 0; rr < 8; ++rr) {
    const uint2* ap = reinterpret_cast<const uint2*>(act_h + (size_t)(r0 + rr) * D_);
    float4*      op = reinterpret_cast<float4*>(out + (size_t)(r0 + rr) * D_);
    #pragma unroll
    for (int i2 = 0; i2 < 2; ++i2) {
      int i = tid + 256 * i2;
      uint2 aw = ap[i];                    // 4 halves = act[4i..4i+3]
      float2 f0 = unpackh2(aw.x);
      float2 f1 = unpackh2(aw.y);
      const float4* sp = reinterpret_cast<const float4*>(scsh + 8 * i);
      float4 s0 = sp[0];
      float4 s1 = sp[1];
      float z0 = fmaf(f0.x, s0.x, s0.y);
      float z1 = fmaf(f0.y, s0.z, s0.w);
      float z2 = fmaf(f1.x, s1.x, s1.y);
      float z3 = fmaf(f1.y, s1.z, s1.w);
      float4 o;
      o.x = 1.0f / (1.0f + __expf(-z0));
      o.y = 1.0f / (1.0f + __expf(-z1));
      o.z = 1.0f / (1.0f + __expf(-z2));
      o.w = 1.0f / (1.0f + __expf(-z3));
      op[i] = o;
    }
  }
}

extern "C" void kernel_launch(void* const* d_in, const int* in_sizes, int n_in,
                              void* d_out, int out_size, void* d_ws, size_t ws_size,
                              hipStream_t stream) {
  const float* xe    = (const float*)d_in[0];
  const float* xi    = (const float*)d_in[1];
  const float* xbr   = (const float*)d_in[2];
  const float* wexc  = (const float*)d_in[3];
  const float* winh  = (const float*)d_in[4];
  const float* wblk  = (const float*)d_in[5];
  const float* gamma = (const float*)d_in[6];
  const float* beta  = (const float*)d_in[7];
  float* out = (float*)d_out;

  char* ws = (char*)d_ws;
  uint4*    muT     = (uint4*)   (ws + 0);         // [13][2048] uint4
  unsigned* so_inh  = (unsigned*)(ws + 425984);
  float*    vi_inh  = (float*)   (ws + 434176);
  float*    wdiag   = (float*)   (ws + 442368);    // ends 475136
  float*    sums_p  = (float*)   (ws + 475136);    // [4][2048] f32
  float*    sumsq_p = (float*)   (ws + 507904);    // [4][2048] f32 (ends 540672)
  __half*   act_h   = (__half*)  (ws + 1048576);   // [4096][2048] f16 = 16 MiB

  hipMemsetAsync(sums_p, 0, 2 * NSL_ * D_ * sizeof(float), stream);

  prep_kernel<<<dim3(4097), dim3(256), 0, stream>>>(
      wexc, winh, wblk, muT, so_inh, vi_inh, wdiag);
  fused_ei<<<dim3(B_ / 4), dim3(512), 0, stream>>>(
      xe, xi, xbr, wdiag, muT, so_inh, vi_inh, act_h, sums_p, sumsq_p);
  tail_kernel<<<dim3(512), dim3(256), 0, stream>>>(
      act_h, out, sums_p, sumsq_p, gamma, beta);
}